// Round 1
// baseline (857.300 us; speedup 1.0000x reference)
//
#include <hip/hip_runtime.h>
#include <stdint.h>

#define T_TOK 8192
#define HD    1024
#define ID    2816
#define NE    8
#define RCAP  17408   // 16384 pairs + up to 8*128 padding

typedef __bf16 bf16x8 __attribute__((ext_vector_type(8)));
typedef float  f32x4  __attribute__((ext_vector_type(4)));

__device__ __forceinline__ unsigned short f2bf(float f) {
  union { float f; unsigned u; } v; v.f = f;
  unsigned r = v.u + 0x7FFFu + ((v.u >> 16) & 1u);  // round-to-nearest-even
  return (unsigned short)(r >> 16);
}

__device__ __forceinline__ void gl16(const void* g, void* l) {
  // async global->LDS, 16B/lane; LDS dest = uniform base + lane*16
  __builtin_amdgcn_global_load_lds((__attribute__((address_space(1))) void*)g,
                                   (__attribute__((address_space(3))) void*)l,
                                   16, 0, 0);
}

// ---------------- K0a: x fp32 -> bf16 ----------------
__global__ void k_cvt_x(const float* __restrict__ x, unsigned short* __restrict__ xb) {
  const int i = blockIdx.x * blockDim.x + threadIdx.x;   // one float4 per thread
  const float4 v = ((const float4*)x)[i];
  ushort4 o;
  o.x = f2bf(v.x); o.y = f2bf(v.y); o.z = f2bf(v.z); o.w = f2bf(v.w);
  ((ushort4*)xb)[i] = o;
}

// ---------------- K0b: transpose + convert weights ----------------
// m<8: Wg[e] [H][I] -> Wgt[e] [I][H]; m<16: Wu; m>=16: Wd [I][H] -> Wdt[e] [H][I]
__global__ void k_transpose(const float* __restrict__ Wg, const float* __restrict__ Wu,
                            const float* __restrict__ Wd,
                            unsigned short* __restrict__ Wgt, unsigned short* __restrict__ Wut,
                            unsigned short* __restrict__ Wdt) {
  const int m = blockIdx.y;
  const float* src; unsigned short* dst; int R, C;
  if (m < 8)       { src = Wg + (size_t)m * HD * ID;        dst = Wgt + (size_t)m * HD * ID;        R = HD; C = ID; }
  else if (m < 16) { src = Wu + (size_t)(m - 8) * HD * ID;  dst = Wut + (size_t)(m - 8) * HD * ID;  R = HD; C = ID; }
  else             { src = Wd + (size_t)(m - 16) * HD * ID; dst = Wdt + (size_t)(m - 16) * HD * ID; R = ID; C = HD; }
  const int tc = C / 64;
  const int tr = blockIdx.x / tc, tcc = blockIdx.x % tc;
  const int r0 = tr * 64, c0 = tcc * 64;
  __shared__ unsigned short tile[64][68];
  const int t = threadIdx.x;
#pragma unroll
  for (int k = 0; k < 4; ++k) {
    const int c = t + k * 256;          // 1024 float4 chunks
    const int row = c >> 4, c4 = c & 15;
    const float4 v = *(const float4*)(src + (size_t)(r0 + row) * C + c0 + c4 * 4);
    tile[row][c4 * 4 + 0] = f2bf(v.x);
    tile[row][c4 * 4 + 1] = f2bf(v.y);
    tile[row][c4 * 4 + 2] = f2bf(v.z);
    tile[row][c4 * 4 + 3] = f2bf(v.w);
  }
  __syncthreads();
  const int orow = t >> 2, seg = t & 3;
  __align__(16) unsigned short tmp[16];
#pragma unroll
  for (int j = 0; j < 16; ++j) tmp[j] = tile[seg * 16 + j][orow];
  unsigned short* dp = dst + (size_t)(c0 + orow) * R + r0 + seg * 16;
  ((uint4*)dp)[0] = ((const uint4*)tmp)[0];
  ((uint4*)dp)[1] = ((const uint4*)tmp)[1];
}

// ---------------- K1: router ----------------
__global__ void k_router(const float* __restrict__ x, const float* __restrict__ Wr,
                         int* __restrict__ cnt, float* __restrict__ psum,
                         int* __restrict__ tok_e, float* __restrict__ tok_w) {
  __shared__ float bp[NE];
  __shared__ int bc[NE];
  const int tid = threadIdx.x;
  if (tid < NE) { bp[tid] = 0.f; bc[tid] = 0; }
  __syncthreads();
  const int lane = tid & 63, w = tid >> 6;
  for (int i = 0; i < 8; ++i) {
    const int t = blockIdx.x * 32 + w * 8 + i;
    float acc[NE] = {0.f, 0.f, 0.f, 0.f, 0.f, 0.f, 0.f, 0.f};
    for (int h = lane; h < HD; h += 64) {
      const float xv = x[(size_t)t * HD + h];
      const float4 w0 = *(const float4*)(Wr + h * 8);
      const float4 w1 = *(const float4*)(Wr + h * 8 + 4);
      acc[0] += xv * w0.x; acc[1] += xv * w0.y; acc[2] += xv * w0.z; acc[3] += xv * w0.w;
      acc[4] += xv * w1.x; acc[5] += xv * w1.y; acc[6] += xv * w1.z; acc[7] += xv * w1.w;
    }
#pragma unroll
    for (int e = 0; e < NE; ++e)
      for (int off = 32; off > 0; off >>= 1)
        acc[e] += __shfl_xor(acc[e], off, 64);
    if (lane == 0) {
      float mx = acc[0];
      for (int e = 1; e < NE; ++e) mx = fmaxf(mx, acc[e]);
      float p[NE], s = 0.f;
      for (int e = 0; e < NE; ++e) { p[e] = __expf(acc[e] - mx); s += p[e]; }
      const float inv = 1.f / s;
      for (int e = 0; e < NE; ++e) p[e] *= inv;
      int e0 = 0;
      for (int e = 1; e < NE; ++e) if (p[e] > p[e0]) e0 = e;
      int e1 = (e0 == 0) ? 1 : 0;
      for (int e = 0; e < NE; ++e) if (e != e0 && p[e] > p[e1]) e1 = e;
      const float v0 = p[e0], v1 = p[e1];
      const float invs = 1.f / (v0 + v1 + 1e-9f);
      tok_e[2 * t] = e0;          tok_e[2 * t + 1] = e1;
      tok_w[2 * t] = v0 * invs;   tok_w[2 * t + 1] = v1 * invs;
      atomicAdd(&bc[e0], 1); atomicAdd(&bc[e1], 1);
      for (int e = 0; e < NE; ++e) atomicAdd(&bp[e], p[e]);
    }
  }
  __syncthreads();
  if (tid < NE) { atomicAdd(&cnt[tid], bc[tid]); atomicAdd(&psum[tid], bp[tid]); }
}

// ---------------- K2: offsets + aux loss + pad sentinels ----------------
__global__ void k_offsets(const int* __restrict__ cnt, const float* __restrict__ psum,
                          int* __restrict__ offp, int* __restrict__ pair_tok,
                          float* __restrict__ pair_w, float* __restrict__ loss_out) {
  __shared__ int soff[NE + 1], scnt[NE];
  if (threadIdx.x == 0) {
    int o = 0;
    for (int e = 0; e < NE; ++e) {
      soff[e] = o; scnt[e] = cnt[e];
      o += (scnt[e] + 127) & ~127;
    }
    soff[NE] = o;
    for (int e = 0; e <= NE; ++e) offp[e] = soff[e];
    float loss = 0.f;
    for (int e = 0; e < NE; ++e) loss += psum[e] * (float)scnt[e];
    loss *= (float)NE * 0.01f / ((float)T_TOK * (float)T_TOK);
    *loss_out = loss;
  }
  __syncthreads();
  for (int e = 0; e < NE; ++e) {
    const int base = soff[e] + scnt[e];
    const int n = soff[e + 1] - base;
    for (int j = threadIdx.x; j < n; j += blockDim.x) {
      pair_tok[base + j] = -1;
      pair_w[base + j] = 0.f;
    }
  }
}

// ---------------- K3: compaction ----------------
__global__ void k_scatter(const int* __restrict__ tok_e, const float* __restrict__ tok_w,
                          const int* __restrict__ offp, int* __restrict__ cursor,
                          int* __restrict__ pair_tok, float* __restrict__ pair_w) {
  const int t = blockIdx.x * 256 + threadIdx.x;
#pragma unroll
  for (int k = 0; k < 2; ++k) {
    const int e = tok_e[2 * t + k];
    const int pos = atomicAdd(&cursor[e], 1);
    const int idx = offp[e] + pos;
    pair_tok[idx] = t;
    pair_w[idx] = tok_w[2 * t + k];
  }
}

// ---------------- K4: stage1 fused gate+up GEMM + SwiGLU ----------------
__launch_bounds__(256, 2)
__global__ void k_stage1(const unsigned short* __restrict__ xb,
                         const unsigned short* __restrict__ Wgt,
                         const unsigned short* __restrict__ Wut,
                         const int* __restrict__ offp,
                         const int* __restrict__ pair_tok,
                         unsigned short* __restrict__ act) {
  __shared__ __align__(16) unsigned short lA[8192];
  __shared__ __align__(16) unsigned short lBg[8192];
  __shared__ __align__(16) unsigned short lBu[8192];
  __shared__ int toks[128];

  const int row0 = blockIdx.y * 128;
  if (row0 >= offp[8]) return;
  int e = 0;
  while (offp[e + 1] <= row0) ++e;
  const int i0 = blockIdx.x * 128;
  const int tid = threadIdx.x;
  if (tid < 128) {
    const int tk = pair_tok[row0 + tid];
    toks[tid] = tk < 0 ? 0 : tk;
  }
  __syncthreads();

  const int lane = tid & 63, w = tid >> 6;
  const unsigned short* gA[4];
  const unsigned short* gBg[4];
  const unsigned short* gBu[4];
  unsigned ldso[4];
  const unsigned short* wgtE = Wgt + (size_t)e * ID * HD;
  const unsigned short* wutE = Wut + (size_t)e * ID * HD;
#pragma unroll
  for (int j = 0; j < 4; ++j) {
    const int row = (w * 4 + j) * 8 + (lane >> 3);
    const int kb = (lane & 7) ^ (row & 7);           // global-side swizzle, LDS stays linear
    gA[j]  = xb + (size_t)toks[row] * HD + kb * 8;
    gBg[j] = wgtE + (size_t)(i0 + row) * HD + kb * 8;
    gBu[j] = wutE + (size_t)(i0 + row) * HD + kb * 8;
    ldso[j] = (unsigned)(w * 4 + j) * 512u;
  }

  const f32x4 zero = {0.f, 0.f, 0.f, 0.f};
  f32x4 accg[4][4], accu[4][4];
#pragma unroll
  for (int a = 0; a < 4; ++a)
#pragma unroll
    for (int b = 0; b < 4; ++b) { accg[a][b] = zero; accu[a][b] = zero; }

  const int wm = (w & 1) * 64, wn = (w >> 1) * 64;
  const int colm = lane & 15, quad = lane >> 4;

  for (int kt = 0; kt < HD / 64; ++kt) {
    __syncthreads();
    const int ko = kt * 64;
#pragma unroll
    for (int j = 0; j < 4; ++j) {
      gl16(gA[j] + ko,  &lA[ldso[j]]);
      gl16(gBg[j] + ko, &lBg[ldso[j]]);
      gl16(gBu[j] + ko, &lBu[ldso[j]]);
    }
    __syncthreads();
#pragma unroll
    for (int kk = 0; kk < 2; ++kk) {
      const int kbl = kk * 4 + quad;
      bf16x8 af[4], bg[4], bu[4];
#pragma unroll
      for (int mf = 0; mf < 4; ++mf) {
        const int r = wm + mf * 16 + colm;
        af[mf] = *(const bf16x8*)&lA[r * 64 + ((kbl ^ (r & 7)) * 8)];
      }
#pragma unroll
      for (int nf = 0; nf < 4; ++nf) {
        const int r = wn + nf * 16 + colm;
        const int o = r * 64 + ((kbl ^ (r & 7)) * 8);
        bg[nf] = *(const bf16x8*)&lBg[o];
        bu[nf] = *(const bf16x8*)&lBu[o];
      }
#pragma unroll
      for (int mf = 0; mf < 4; ++mf)
#pragma unroll
        for (int nf = 0; nf < 4; ++nf) {
          accg[mf][nf] = __builtin_amdgcn_mfma_f32_16x16x32_bf16(af[mf], bg[nf], accg[mf][nf], 0, 0, 0);
          accu[mf][nf] = __builtin_amdgcn_mfma_f32_16x16x32_bf16(af[mf], bu[nf], accu[mf][nf], 0, 0, 0);
        }
    }
  }

#pragma unroll
  for (int mf = 0; mf < 4; ++mf) {
#pragma unroll
    for (int r = 0; r < 4; ++r) {
      const int orow = row0 + wm + mf * 16 + quad * 4 + r;
      unsigned short* arow = act + (size_t)orow * ID + i0 + wn + colm;
#pragma unroll
      for (int nf = 0; nf < 4; ++nf) {
        const float g = accg[mf][nf][r];
        const float u = accu[mf][nf][r];
        const float h = (g / (1.f + __expf(-g))) * u;   // silu(g)*u
        arow[nf * 16] = f2bf(h);
      }
    }
  }
}

// ---------------- K5: stage2 down GEMM + weighted scatter ----------------
__launch_bounds__(256, 2)
__global__ void k_stage2(const unsigned short* __restrict__ act,
                         const unsigned short* __restrict__ Wdt,
                         const int* __restrict__ offp,
                         const int* __restrict__ pair_tok,
                         const float* __restrict__ pair_w,
                         float* __restrict__ out) {
  __shared__ __align__(16) unsigned short lA[8192];
  __shared__ __align__(16) unsigned short lB[8192];
  __shared__ int toks[128];
  __shared__ float wts[128];

  const int row0 = blockIdx.y * 128;
  if (row0 >= offp[8]) return;
  int e = 0;
  while (offp[e + 1] <= row0) ++e;
  const int h0 = blockIdx.x * 128;
  const int tid = threadIdx.x;
  if (tid < 128) {
    toks[tid] = pair_tok[row0 + tid];
    wts[tid] = pair_w[row0 + tid];
  }
  const int lane = tid & 63, w = tid >> 6;
  const unsigned short* gA[4];
  const unsigned short* gB[4];
  unsigned ldso[4];
  const unsigned short* wdE = Wdt + (size_t)e * HD * ID;
#pragma unroll
  for (int j = 0; j < 4; ++j) {
    const int row = (w * 4 + j) * 8 + (lane >> 3);
    const int kb = (lane & 7) ^ (row & 7);
    gA[j] = act + (size_t)(row0 + row) * ID + kb * 8;
    gB[j] = wdE + (size_t)(h0 + row) * ID + kb * 8;
    ldso[j] = (unsigned)(w * 4 + j) * 512u;
  }

  const f32x4 zero = {0.f, 0.f, 0.f, 0.f};
  f32x4 acc[4][4];
#pragma unroll
  for (int a = 0; a < 4; ++a)
#pragma unroll
    for (int b = 0; b < 4; ++b) acc[a][b] = zero;

  const int wm = (w & 1) * 64, wn = (w >> 1) * 64;
  const int colm = lane & 15, quad = lane >> 4;

  for (int kt = 0; kt < ID / 64; ++kt) {
    __syncthreads();
    const int ko = kt * 64;
#pragma unroll
    for (int j = 0; j < 4; ++j) {
      gl16(gA[j] + ko, &lA[ldso[j]]);
      gl16(gB[j] + ko, &lB[ldso[j]]);
    }
    __syncthreads();
#pragma unroll
    for (int kk = 0; kk < 2; ++kk) {
      const int kbl = kk * 4 + quad;
      bf16x8 af[4], bf_[4];
#pragma unroll
      for (int mf = 0; mf < 4; ++mf) {
        const int r = wm + mf * 16 + colm;
        af[mf] = *(const bf16x8*)&lA[r * 64 + ((kbl ^ (r & 7)) * 8)];
      }
#pragma unroll
      for (int nf = 0; nf < 4; ++nf) {
        const int r = wn + nf * 16 + colm;
        bf_[nf] = *(const bf16x8*)&lB[r * 64 + ((kbl ^ (r & 7)) * 8)];
      }
#pragma unroll
      for (int mf = 0; mf < 4; ++mf)
#pragma unroll
        for (int nf = 0; nf < 4; ++nf)
          acc[mf][nf] = __builtin_amdgcn_mfma_f32_16x16x32_bf16(af[mf], bf_[nf], acc[mf][nf], 0, 0, 0);
    }
  }

#pragma unroll
  for (int mf = 0; mf < 4; ++mf) {
#pragma unroll
    for (int r = 0; r < 4; ++r) {
      const int lrow = wm + mf * 16 + quad * 4 + r;
      const int t = toks[lrow];
      if (t < 0) continue;
      const float wt = wts[lrow];
      float* orow = out + (size_t)t * HD + h0 + wn + colm;
#pragma unroll
      for (int nf = 0; nf < 4; ++nf)
        atomicAdd(&orow[nf * 16], wt * acc[mf][nf][r]);
    }
  }
}

extern "C" void kernel_launch(void* const* d_in, const int* in_sizes, int n_in,
                              void* d_out, int out_size, void* d_ws, size_t ws_size,
                              hipStream_t stream) {
  const float* x  = (const float*)d_in[0];
  const float* Wr = (const float*)d_in[1];
  const float* Wg = (const float*)d_in[2];
  const float* Wu = (const float*)d_in[3];
  const float* Wd = (const float*)d_in[4];
  float* out = (float*)d_out;

  char* ws = (char*)d_ws;
  const size_t off_xb  = 256;
  const size_t sz_xb   = (size_t)T_TOK * HD * 2;
  const size_t sz_w    = (size_t)NE * HD * ID * 2;
  const size_t off_wgt = off_xb + sz_xb;
  const size_t off_wut = off_wgt + sz_w;
  const size_t off_wdt = off_wut + sz_w;
  const size_t off_act = off_wdt + sz_w;
  const size_t sz_act  = (size_t)RCAP * ID * 2;
  const size_t off_ptk = off_act + sz_act;
  const size_t off_pw  = off_ptk + (size_t)RCAP * 4;
  const size_t off_te  = off_pw + (size_t)RCAP * 4;
  const size_t off_tw  = off_te + (size_t)T_TOK * 2 * 4;
  const size_t need    = off_tw + (size_t)T_TOK * 2 * 4;
  if (ws_size < need) return;  // workspace too small; fail loudly via validation

  int*   cnt    = (int*)(ws + 0);
  float* psum   = (float*)(ws + 32);
  int*   cursor = (int*)(ws + 64);
  int*   offp   = (int*)(ws + 96);
  unsigned short* xb  = (unsigned short*)(ws + off_xb);
  unsigned short* Wgt = (unsigned short*)(ws + off_wgt);
  unsigned short* Wut = (unsigned short*)(ws + off_wut);
  unsigned short* Wdt = (unsigned short*)(ws + off_wdt);
  unsigned short* act = (unsigned short*)(ws + off_act);
  int*   pair_tok = (int*)(ws + off_ptk);
  float* pair_w   = (float*)(ws + off_pw);
  int*   tok_e    = (int*)(ws + off_te);
  float* tok_w    = (float*)(ws + off_tw);

  hipMemsetAsync(ws, 0, 256, stream);
  hipMemsetAsync(out, 0, (size_t)T_TOK * HD * sizeof(float), stream);

  k_cvt_x<<<(T_TOK * HD / 4) / 256, 256, 0, stream>>>(x, xb);
  k_transpose<<<dim3(704, 24), 256, 0, stream>>>(Wg, Wu, Wd, Wgt, Wut, Wdt);
  k_router<<<T_TOK / 32, 256, 0, stream>>>(x, Wr, cnt, psum, tok_e, tok_w);
  k_offsets<<<1, 256, 0, stream>>>(cnt, psum, offp, pair_tok, pair_w, out + (size_t)T_TOK * HD);
  k_scatter<<<T_TOK / 256, 256, 0, stream>>>(tok_e, tok_w, offp, cursor, pair_tok, pair_w);
  k_stage1<<<dim3(ID / 128, RCAP / 128), 256, 0, stream>>>(xb, Wgt, Wut, offp, pair_tok, act);
  k_stage2<<<dim3(HD / 128, RCAP / 128), 256, 0, stream>>>(act, Wdt, offp, pair_tok, pair_w, out);
}

// Round 2
// 837.021 us; speedup vs baseline: 1.0242x; 1.0242x over previous
//
#include <hip/hip_runtime.h>
#include <stdint.h>

#define T_TOK 8192
#define HD    1024
#define ID    2816
#define NE    8
#define RCAP  17408   // 16384 pairs + up to 8*128 padding

typedef __bf16 bf16x8 __attribute__((ext_vector_type(8)));
typedef float  f32x4  __attribute__((ext_vector_type(4)));

__device__ __forceinline__ unsigned short f2bf(float f) {
  union { float f; unsigned u; } v; v.f = f;
  unsigned r = v.u + 0x7FFFu + ((v.u >> 16) & 1u);  // round-to-nearest-even
  return (unsigned short)(r >> 16);
}

__device__ __forceinline__ void gl16(const void* g, void* l) {
  __builtin_amdgcn_global_load_lds((__attribute__((address_space(1))) void*)g,
                                   (__attribute__((address_space(3))) void*)l,
                                   16, 0, 0);
}

// ---------------- K0a: x fp32 -> bf16 ----------------
__global__ void k_cvt_x(const float* __restrict__ x, unsigned short* __restrict__ xb) {
  const int i = blockIdx.x * blockDim.x + threadIdx.x;
  const float4 v = ((const float4*)x)[i];
  ushort4 o;
  o.x = f2bf(v.x); o.y = f2bf(v.y); o.z = f2bf(v.z); o.w = f2bf(v.w);
  ((ushort4*)xb)[i] = o;
}

// ---------------- K0b: transpose + convert weights ----------------
// 4x4 register-block transpose, XOR slot swizzle in LDS (b64 ops, <=4-way)
__global__ void k_transpose(const float* __restrict__ Wg, const float* __restrict__ Wu,
                            const float* __restrict__ Wd,
                            unsigned short* __restrict__ Wgt, unsigned short* __restrict__ Wut,
                            unsigned short* __restrict__ Wdt) {
  const int m = blockIdx.y;
  const float* src; unsigned short* dst; int R, C;
  if (m < 8)       { src = Wg + (size_t)m * HD * ID;        dst = Wgt + (size_t)m * HD * ID;        R = HD; C = ID; }
  else if (m < 16) { src = Wu + (size_t)(m - 8) * HD * ID;  dst = Wut + (size_t)(m - 8) * HD * ID;  R = HD; C = ID; }
  else             { src = Wd + (size_t)(m - 16) * HD * ID; dst = Wdt + (size_t)(m - 16) * HD * ID; R = ID; C = HD; }
  const int tc = C / 64;
  const int tr = blockIdx.x / tc, tcc = blockIdx.x % tc;
  const int r0 = tr * 64, c0 = tcc * 64;
  __shared__ __align__(16) unsigned short tl[64 * 64];  // [dst_row][slot^swz]
  const int t = threadIdx.x;
  const int rb = t >> 4;       // source row block 0..15
  const int c4 = t & 15;       // source col block 0..15
  const float* sp = src + (size_t)(r0 + rb * 4) * C + c0 + c4 * 4;
  float4 v[4];
#pragma unroll
  for (int i = 0; i < 4; ++i) v[i] = *(const float4*)(sp + (size_t)i * C);
  const float* vf = (const float*)v;
#pragma unroll
  for (int q = 0; q < 4; ++q) {
    const int c = c4 * 4 + q;                 // dst row
    ushort4 o;
    o.x = f2bf(vf[0 * 4 + q]); o.y = f2bf(vf[1 * 4 + q]);
    o.z = f2bf(vf[2 * 4 + q]); o.w = f2bf(vf[3 * 4 + q]);
    *(ushort4*)&tl[c * 64 + ((rb ^ (c & 15)) * 4)] = o;   // dst cols rb*4..rb*4+3
  }
  __syncthreads();
  const int orow = t >> 2, seg = t & 3;
  __align__(16) unsigned short tmp[16];
#pragma unroll
  for (int mI = 0; mI < 4; ++mI) {
    const int s = seg * 4 + mI;
    *(ushort4*)&tmp[mI * 4] = *(const ushort4*)&tl[orow * 64 + ((s ^ (orow & 15)) * 4)];
  }
  unsigned short* dp = dst + (size_t)(c0 + orow) * R + r0 + seg * 16;
  ((uint4*)dp)[0] = ((const uint4*)tmp)[0];
  ((uint4*)dp)[1] = ((const uint4*)tmp)[1];
}

// ---------------- K1: router (1 token per wave) ----------------
__global__ void k_router(const float* __restrict__ x, const float* __restrict__ Wr,
                         int* __restrict__ cnt, float* __restrict__ psum,
                         int* __restrict__ tok_e, float* __restrict__ tok_w) {
  __shared__ float bp[NE];
  __shared__ int bc[NE];
  const int tid = threadIdx.x;
  if (tid < NE) { bp[tid] = 0.f; bc[tid] = 0; }
  __syncthreads();
  const int lane = tid & 63, w = tid >> 6;
  const int t = blockIdx.x * 4 + w;
  float acc[NE] = {0.f, 0.f, 0.f, 0.f, 0.f, 0.f, 0.f, 0.f};
  for (int h = lane; h < HD; h += 64) {
    const float xv = x[(size_t)t * HD + h];
    const float4 w0 = *(const float4*)(Wr + h * 8);
    const float4 w1 = *(const float4*)(Wr + h * 8 + 4);
    acc[0] += xv * w0.x; acc[1] += xv * w0.y; acc[2] += xv * w0.z; acc[3] += xv * w0.w;
    acc[4] += xv * w1.x; acc[5] += xv * w1.y; acc[6] += xv * w1.z; acc[7] += xv * w1.w;
  }
#pragma unroll
  for (int e = 0; e < NE; ++e)
    for (int off = 32; off > 0; off >>= 1)
      acc[e] += __shfl_xor(acc[e], off, 64);
  if (lane == 0) {
    float mx = acc[0];
    for (int e = 1; e < NE; ++e) mx = fmaxf(mx, acc[e]);
    float p[NE], s = 0.f;
    for (int e = 0; e < NE; ++e) { p[e] = __expf(acc[e] - mx); s += p[e]; }
    const float inv = 1.f / s;
    for (int e = 0; e < NE; ++e) p[e] *= inv;
    int e0 = 0;
    for (int e = 1; e < NE; ++e) if (p[e] > p[e0]) e0 = e;
    int e1 = (e0 == 0) ? 1 : 0;
    for (int e = 0; e < NE; ++e) if (e != e0 && p[e] > p[e1]) e1 = e;
    const float v0 = p[e0], v1 = p[e1];
    const float invs = 1.f / (v0 + v1 + 1e-9f);
    tok_e[2 * t] = e0;          tok_e[2 * t + 1] = e1;
    tok_w[2 * t] = v0 * invs;   tok_w[2 * t + 1] = v1 * invs;
    atomicAdd(&bc[e0], 1); atomicAdd(&bc[e1], 1);
    for (int e = 0; e < NE; ++e) atomicAdd(&bp[e], p[e]);
  }
  __syncthreads();
  if (tid < NE) { atomicAdd(&cnt[tid], bc[tid]); atomicAdd(&psum[tid], bp[tid]); }
}

// ---------------- K2: offsets + aux loss + pad sentinels ----------------
__global__ void k_offsets(const int* __restrict__ cnt, const float* __restrict__ psum,
                          int* __restrict__ offp, int* __restrict__ pair_tok,
                          float* __restrict__ pair_w, float* __restrict__ loss_out) {
  __shared__ int soff[NE + 1], scnt[NE];
  if (threadIdx.x == 0) {
    int o = 0;
    for (int e = 0; e < NE; ++e) {
      soff[e] = o; scnt[e] = cnt[e];
      o += (scnt[e] + 127) & ~127;
    }
    soff[NE] = o;
    for (int e = 0; e <= NE; ++e) offp[e] = soff[e];
    float loss = 0.f;
    for (int e = 0; e < NE; ++e) loss += psum[e] * (float)scnt[e];
    loss *= (float)NE * 0.01f / ((float)T_TOK * (float)T_TOK);
    *loss_out = loss;
  }
  __syncthreads();
  for (int e = 0; e < NE; ++e) {
    const int base = soff[e] + scnt[e];
    const int n = soff[e + 1] - base;
    for (int j = threadIdx.x; j < n; j += blockDim.x) {
      pair_tok[base + j] = -1;
      pair_w[base + j] = 0.f;
    }
  }
}

// ---------------- K3: compaction (+ inverse map) ----------------
__global__ void k_scatter(const int* __restrict__ tok_e, const float* __restrict__ tok_w,
                          const int* __restrict__ offp, int* __restrict__ cursor,
                          int* __restrict__ pair_tok, float* __restrict__ pair_w,
                          int* __restrict__ inv_p) {
  const int t = blockIdx.x * 256 + threadIdx.x;
#pragma unroll
  for (int k = 0; k < 2; ++k) {
    const int e = tok_e[2 * t + k];
    const int pos = atomicAdd(&cursor[e], 1);
    const int idx = offp[e] + pos;
    pair_tok[idx] = t;
    pair_w[idx] = tok_w[2 * t + k];
    inv_p[2 * t + k] = idx;
  }
}

// ---------------- K4: stage1 fused gate+up GEMM + SwiGLU ----------------
__launch_bounds__(256, 2)
__global__ void k_stage1(const unsigned short* __restrict__ xb,
                         const unsigned short* __restrict__ Wgt,
                         const unsigned short* __restrict__ Wut,
                         const int* __restrict__ offp,
                         const int* __restrict__ pair_tok,
                         unsigned short* __restrict__ act) {
  __shared__ __align__(16) unsigned short lA[8192];
  __shared__ __align__(16) unsigned short lBg[8192];
  __shared__ __align__(16) unsigned short lBu[8192];
  __shared__ int toks[128];

  const int row0 = blockIdx.y * 128;
  if (row0 >= offp[8]) return;
  int e = 0;
  while (offp[e + 1] <= row0) ++e;
  const int i0 = blockIdx.x * 128;
  const int tid = threadIdx.x;
  if (tid < 128) {
    const int tk = pair_tok[row0 + tid];
    toks[tid] = tk < 0 ? 0 : tk;
  }
  __syncthreads();

  const int lane = tid & 63, w = tid >> 6;
  const unsigned short* gA[4];
  const unsigned short* gBg[4];
  const unsigned short* gBu[4];
  unsigned ldso[4];
  const unsigned short* wgtE = Wgt + (size_t)e * ID * HD;
  const unsigned short* wutE = Wut + (size_t)e * ID * HD;
#pragma unroll
  for (int j = 0; j < 4; ++j) {
    const int row = (w * 4 + j) * 8 + (lane >> 3);
    const int kb = (lane & 7) ^ (row & 7);
    gA[j]  = xb + (size_t)toks[row] * HD + kb * 8;
    gBg[j] = wgtE + (size_t)(i0 + row) * HD + kb * 8;
    gBu[j] = wutE + (size_t)(i0 + row) * HD + kb * 8;
    ldso[j] = (unsigned)(w * 4 + j) * 512u;
  }

  const f32x4 zero = {0.f, 0.f, 0.f, 0.f};
  f32x4 accg[4][4], accu[4][4];
#pragma unroll
  for (int a = 0; a < 4; ++a)
#pragma unroll
    for (int b = 0; b < 4; ++b) { accg[a][b] = zero; accu[a][b] = zero; }

  const int wm = (w & 1) * 64, wn = (w >> 1) * 64;
  const int colm = lane & 15, quad = lane >> 4;

  for (int kt = 0; kt < HD / 64; ++kt) {
    __syncthreads();
    const int ko = kt * 64;
#pragma unroll
    for (int j = 0; j < 4; ++j) {
      gl16(gA[j] + ko,  &lA[ldso[j]]);
      gl16(gBg[j] + ko, &lBg[ldso[j]]);
      gl16(gBu[j] + ko, &lBu[ldso[j]]);
    }
    __syncthreads();
#pragma unroll
    for (int kk = 0; kk < 2; ++kk) {
      const int kbl = kk * 4 + quad;
      bf16x8 af[4], bg[4], bu[4];
#pragma unroll
      for (int mf = 0; mf < 4; ++mf) {
        const int r = wm + mf * 16 + colm;
        af[mf] = *(const bf16x8*)&lA[r * 64 + ((kbl ^ (r & 7)) * 8)];
      }
#pragma unroll
      for (int nf = 0; nf < 4; ++nf) {
        const int r = wn + nf * 16 + colm;
        const int o = r * 64 + ((kbl ^ (r & 7)) * 8);
        bg[nf] = *(const bf16x8*)&lBg[o];
        bu[nf] = *(const bf16x8*)&lBu[o];
      }
#pragma unroll
      for (int mf = 0; mf < 4; ++mf)
#pragma unroll
        for (int nf = 0; nf < 4; ++nf) {
          accg[mf][nf] = __builtin_amdgcn_mfma_f32_16x16x32_bf16(af[mf], bg[nf], accg[mf][nf], 0, 0, 0);
          accu[mf][nf] = __builtin_amdgcn_mfma_f32_16x16x32_bf16(af[mf], bu[nf], accu[mf][nf], 0, 0, 0);
        }
    }
  }

#pragma unroll
  for (int mf = 0; mf < 4; ++mf) {
#pragma unroll
    for (int r = 0; r < 4; ++r) {
      const int orow = row0 + wm + mf * 16 + quad * 4 + r;
      unsigned short* arow = act + (size_t)orow * ID + i0 + wn + colm;
#pragma unroll
      for (int nf = 0; nf < 4; ++nf) {
        const float g = accg[mf][nf][r];
        const float u = accu[mf][nf][r];
        const float h = (g / (1.f + __expf(-g))) * u;
        arow[nf * 16] = f2bf(h);
      }
    }
  }
}

// ---------------- K5 core: stage2 down GEMM ----------------
template <bool USE_CONTRIB>
__launch_bounds__(256, 2)
__global__ void k_stage2_t(const unsigned short* __restrict__ act,
                           const unsigned short* __restrict__ Wdt,
                           const int* __restrict__ offp,
                           const int* __restrict__ pair_tok,
                           const float* __restrict__ pair_w,
                           float* __restrict__ contrib,   // USE_CONTRIB: [RCAP][HD]
                           float* __restrict__ out) {     // !USE_CONTRIB: atomic path
  __shared__ __align__(16) unsigned short lA[8192];
  __shared__ __align__(16) unsigned short lB[8192];
  __shared__ int toks[128];
  __shared__ float wts[128];

  const int row0 = blockIdx.y * 128;
  if (row0 >= offp[8]) return;
  int e = 0;
  while (offp[e + 1] <= row0) ++e;
  const int h0 = blockIdx.x * 128;
  const int tid = threadIdx.x;
  if (!USE_CONTRIB && tid < 128) {
    toks[tid] = pair_tok[row0 + tid];
    wts[tid] = pair_w[row0 + tid];
  }
  const int lane = tid & 63, w = tid >> 6;
  const unsigned short* gA[4];
  const unsigned short* gB[4];
  unsigned ldso[4];
  const unsigned short* wdE = Wdt + (size_t)e * HD * ID;
#pragma unroll
  for (int j = 0; j < 4; ++j) {
    const int row = (w * 4 + j) * 8 + (lane >> 3);
    const int kb = (lane & 7) ^ (row & 7);
    gA[j] = act + (size_t)(row0 + row) * ID + kb * 8;
    gB[j] = wdE + (size_t)(h0 + row) * ID + kb * 8;
    ldso[j] = (unsigned)(w * 4 + j) * 512u;
  }

  const f32x4 zero = {0.f, 0.f, 0.f, 0.f};
  f32x4 acc[4][4];
#pragma unroll
  for (int a = 0; a < 4; ++a)
#pragma unroll
    for (int b = 0; b < 4; ++b) acc[a][b] = zero;

  const int wm = (w & 1) * 64, wn = (w >> 1) * 64;
  const int colm = lane & 15, quad = lane >> 4;

  for (int kt = 0; kt < ID / 64; ++kt) {
    __syncthreads();
    const int ko = kt * 64;
#pragma unroll
    for (int j = 0; j < 4; ++j) {
      gl16(gA[j] + ko, &lA[ldso[j]]);
      gl16(gB[j] + ko, &lB[ldso[j]]);
    }
    __syncthreads();
#pragma unroll
    for (int kk = 0; kk < 2; ++kk) {
      const int kbl = kk * 4 + quad;
      bf16x8 af[4], bf_[4];
#pragma unroll
      for (int mf = 0; mf < 4; ++mf) {
        const int r = wm + mf * 16 + colm;
        af[mf] = *(const bf16x8*)&lA[r * 64 + ((kbl ^ (r & 7)) * 8)];
      }
#pragma unroll
      for (int nf = 0; nf < 4; ++nf) {
        const int r = wn + nf * 16 + colm;
        bf_[nf] = *(const bf16x8*)&lB[r * 64 + ((kbl ^ (r & 7)) * 8)];
      }
#pragma unroll
      for (int mf = 0; mf < 4; ++mf)
#pragma unroll
        for (int nf = 0; nf < 4; ++nf)
          acc[mf][nf] = __builtin_amdgcn_mfma_f32_16x16x32_bf16(af[mf], bf_[nf], acc[mf][nf], 0, 0, 0);
    }
  }

#pragma unroll
  for (int mf = 0; mf < 4; ++mf) {
#pragma unroll
    for (int r = 0; r < 4; ++r) {
      const int lrow = wm + mf * 16 + quad * 4 + r;
      if (USE_CONTRIB) {
        float* crow = contrib + (size_t)(row0 + lrow) * HD + h0 + wn + colm;
#pragma unroll
        for (int nf = 0; nf < 4; ++nf)
          crow[nf * 16] = acc[mf][nf][r];
      } else {
        const int t = toks[lrow];
        if (t < 0) continue;
        const float wt = wts[lrow];
        float* orow = out + (size_t)t * HD + h0 + wn + colm;
#pragma unroll
        for (int nf = 0; nf < 4; ++nf)
          atomicAdd(&orow[nf * 16], wt * acc[mf][nf][r]);
      }
    }
  }
}

// ---------------- K6: combine (contrib path) ----------------
__global__ void k_combine(const float* __restrict__ contrib, const int* __restrict__ inv_p,
                          const float* __restrict__ tok_w, float* __restrict__ out) {
  const int t = blockIdx.x;
  const int h4 = threadIdx.x;
  const int p0 = inv_p[2 * t], p1 = inv_p[2 * t + 1];
  const float w0 = tok_w[2 * t], w1 = tok_w[2 * t + 1];
  const float4 a = ((const float4*)(contrib + (size_t)p0 * HD))[h4];
  const float4 b = ((const float4*)(contrib + (size_t)p1 * HD))[h4];
  float4 o;
  o.x = w0 * a.x + w1 * b.x;
  o.y = w0 * a.y + w1 * b.y;
  o.z = w0 * a.z + w1 * b.z;
  o.w = w0 * a.w + w1 * b.w;
  ((float4*)(out + (size_t)t * HD))[h4] = o;
}

extern "C" void kernel_launch(void* const* d_in, const int* in_sizes, int n_in,
                              void* d_out, int out_size, void* d_ws, size_t ws_size,
                              hipStream_t stream) {
  const float* x  = (const float*)d_in[0];
  const float* Wr = (const float*)d_in[1];
  const float* Wg = (const float*)d_in[2];
  const float* Wu = (const float*)d_in[3];
  const float* Wd = (const float*)d_in[4];
  float* out = (float*)d_out;

  char* ws = (char*)d_ws;
  const size_t off_xb  = 256;
  const size_t sz_xb   = (size_t)T_TOK * HD * 2;
  const size_t sz_w    = (size_t)NE * HD * ID * 2;
  const size_t off_wgt = off_xb + sz_xb;
  const size_t off_wut = off_wgt + sz_w;
  const size_t off_wdt = off_wut + sz_w;
  const size_t off_act = off_wdt + sz_w;
  const size_t sz_act  = (size_t)RCAP * ID * 2;
  const size_t off_ptk = off_act + sz_act;
  const size_t off_pw  = off_ptk + (size_t)RCAP * 4;
  const size_t off_te  = off_pw + (size_t)RCAP * 4;
  const size_t off_tw  = off_te + (size_t)T_TOK * 2 * 4;
  const size_t off_ip  = off_tw + (size_t)T_TOK * 2 * 4;
  const size_t off_ctb = off_ip + (size_t)T_TOK * 2 * 4;
  const size_t need_base = off_ctb;
  const size_t need_full = off_ctb + (size_t)RCAP * HD * 4;
  if (ws_size < need_base) return;
  const bool use_contrib = (ws_size >= need_full);

  int*   cnt    = (int*)(ws + 0);
  float* psum   = (float*)(ws + 32);
  int*   cursor = (int*)(ws + 64);
  int*   offp   = (int*)(ws + 96);
  unsigned short* xb  = (unsigned short*)(ws + off_xb);
  unsigned short* Wgt = (unsigned short*)(ws + off_wgt);
  unsigned short* Wut = (unsigned short*)(ws + off_wut);
  unsigned short* Wdt = (unsigned short*)(ws + off_wdt);
  unsigned short* act = (unsigned short*)(ws + off_act);
  int*   pair_tok = (int*)(ws + off_ptk);
  float* pair_w   = (float*)(ws + off_pw);
  int*   tok_e    = (int*)(ws + off_te);
  float* tok_w    = (float*)(ws + off_tw);
  int*   inv_p    = (int*)(ws + off_ip);
  float* contrib  = (float*)(ws + off_ctb);

  hipMemsetAsync(ws, 0, 256, stream);
  if (!use_contrib)
    hipMemsetAsync(out, 0, (size_t)T_TOK * HD * sizeof(float), stream);

  k_cvt_x<<<(T_TOK * HD / 4) / 256, 256, 0, stream>>>(x, xb);
  k_transpose<<<dim3(704, 24), 256, 0, stream>>>(Wg, Wu, Wd, Wgt, Wut, Wdt);
  k_router<<<T_TOK / 4, 256, 0, stream>>>(x, Wr, cnt, psum, tok_e, tok_w);
  k_offsets<<<1, 256, 0, stream>>>(cnt, psum, offp, pair_tok, pair_w, out + (size_t)T_TOK * HD);
  k_scatter<<<T_TOK / 256, 256, 0, stream>>>(tok_e, tok_w, offp, cursor, pair_tok, pair_w, inv_p);
  k_stage1<<<dim3(ID / 128, RCAP / 128), 256, 0, stream>>>(xb, Wgt, Wut, offp, pair_tok, act);
  if (use_contrib) {
    k_stage2_t<true><<<dim3(HD / 128, RCAP / 128), 256, 0, stream>>>(act, Wdt, offp, pair_tok, pair_w, contrib, out);
    k_combine<<<T_TOK, 256, 0, stream>>>(contrib, inv_p, tok_w, out);
  } else {
    k_stage2_t<false><<<dim3(HD / 128, RCAP / 128), 256, 0, stream>>>(act, Wdt, offp, pair_tok, pair_w, contrib, out);
  }
}